// Round 1
// baseline (282.190 us; speedup 1.0000x reference)
//
#include <hip/hip_runtime.h>
#include <math.h>

// MFA Woodbury log-likelihood, restructured:
//   per_comp[k,n] = c0_k + x_n.w_k - 0.5*(x_n^2).iD_k + 0.5*||G_k^T x_n - h_k||^2
//   out[n] = logsumexp_k per_comp[k,n]
// where L_k = I + A^T diag(iD) A = C C^T (Cholesky),
//   G_k = (diag(iD_k) A_k) C_k^{-T}   (512x64, via forward substitution)
//   h_k = C_k^{-1} (A_k^T diag(iD_k) MU_k)
//   c0_k = PI_k - 0.5*(d*log(2pi) + logdetL - sum log iD + sum iD*MU^2)
// Big GEMM x(4096x512) @ Gbig(512x8192) in bf16 MFMA, fused SSQ epilogue.

#define KC 128
#define DF 512
#define LF 64
#define NN 4096

typedef __attribute__((ext_vector_type(8))) short short8;
typedef __attribute__((ext_vector_type(4))) float f32x4;

static __device__ __forceinline__ unsigned short bfr(float f) {
  union { float f; unsigned u; } v; v.f = f;
  return (unsigned short)((v.u + 0x7FFFu + ((v.u >> 16) & 1u)) >> 16);
}

static __device__ __forceinline__ void ldst16(void* lds, const void* g) {
  __builtin_amdgcn_global_load_lds((const __attribute__((address_space(1))) void*)g,
                                   (__attribute__((address_space(3))) void*)lds,
                                   16, 0, 0);
}

// ---------------- X: x -> bf16, x^2 -> bf16 ----------------
__global__ __launch_bounds__(256) void mfa_convert(const float* __restrict__ x,
                                                   unsigned short* __restrict__ xbf,
                                                   unsigned short* __restrict__ x2bf) {
  int idx = blockIdx.x * 256 + threadIdx.x;           // float4 index, grid covers N*DF/4
  float4 v = reinterpret_cast<const float4*>(x)[idx];
  ushort4 a, b;
  a.x = bfr(v.x); a.y = bfr(v.y); a.z = bfr(v.z); a.w = bfr(v.w);
  b.x = bfr(v.x * v.x); b.y = bfr(v.y * v.y); b.z = bfr(v.z * v.z); b.w = bfr(v.w * v.w);
  reinterpret_cast<ushort4*>(xbf)[idx] = a;
  reinterpret_cast<ushort4*>(x2bf)[idx] = b;
}

// ---------------- S1: per-k stats ----------------
__global__ __launch_bounds__(256) void mfa_stats(const float* __restrict__ MU,
                                                 const float* __restrict__ Dp,
                                                 const float* __restrict__ A,
                                                 const float* __restrict__ PI,
                                                 float* __restrict__ iDf,
                                                 unsigned short* __restrict__ iDbf,
                                                 unsigned short* __restrict__ wbf,
                                                 float* __restrict__ m2ws,
                                                 float* __restrict__ c0a) {
  int k = blockIdx.x, tid = threadIdx.x;
  __shared__ float iDs[DF];
  __shared__ float redA[256];
  __shared__ float redB[256];
  float slog = 0.f, smu2 = 0.f;
  for (int d = tid; d < DF; d += 256) {
    float Dv = Dp[k * DF + d];
    float id = 1.f / (Dv * Dv);
    iDf[k * DF + d] = id;
    iDs[d] = id;
    iDbf[k * DF + d] = bfr(id);
    float mu = MU[k * DF + d];
    wbf[k * DF + d] = bfr(id * mu);
    slog += logf(id);
    smu2 += id * mu * mu;
  }
  redA[tid] = slog; redB[tid] = smu2;
  __syncthreads();
  for (int s = 128; s > 0; s >>= 1) {
    if (tid < s) { redA[tid] += redA[tid + s]; redB[tid] += redB[tid + s]; }
    __syncthreads();
  }
  if (tid == 0)
    c0a[k] = PI[k] - 0.5f * (DF * 1.8378770664093453f + redB[0] - redA[0]);
  __syncthreads();
  // m2[i] = sum_d A[d][i]*iD[d]*MU[d]
  int i = tid & 63, ch = tid >> 6;
  float m2acc = 0.f;
  for (int dd = 0; dd < 128; ++dd) {
    int d = ch * 128 + dd;
    float a = A[(k * DF + d) * LF + i];
    m2acc += a * iDs[d] * MU[k * DF + d];
  }
  redA[tid] = m2acc;
  __syncthreads();
  if (tid < 64)
    m2ws[k * 64 + tid] = redA[tid] + redA[tid + 64] + redA[tid + 128] + redA[tid + 192];
}

// ---------------- S2: Lmat = I + A^T diag(iD) A ----------------
__global__ __launch_bounds__(256) void mfa_lmat(const float* __restrict__ A,
                                                const float* __restrict__ iDf,
                                                float* __restrict__ Lmat) {
  int k = blockIdx.x, ib = blockIdx.y * 16, tid = threadIdx.x;
  __shared__ float As2[64 * 64];
  __shared__ float iDs2[64];
  int ti = tid >> 5, tj = tid & 31;  // rows i=ib+2ti+{0,1}, cols j=2tj+{0,1}
  float acc00 = 0.f, acc01 = 0.f, acc10 = 0.f, acc11 = 0.f;
  for (int dc = 0; dc < 8; ++dc) {
    __syncthreads();
    const float4* Ak = reinterpret_cast<const float4*>(A + (size_t)(k * DF + dc * 64) * LF);
    for (int idx = tid; idx < 1024; idx += 256)
      reinterpret_cast<float4*>(As2)[idx] = Ak[idx];
    if (tid < 64) iDs2[tid] = iDf[k * DF + dc * 64 + tid];
    __syncthreads();
#pragma unroll 16
    for (int d = 0; d < 64; ++d) {
      float idv = iDs2[d];
      const float2* row = reinterpret_cast<const float2*>(&As2[d * 64]);
      float2 a2 = row[(ib >> 1) + ti];
      float2 b2 = row[tj];
      float b0 = b2.x * idv, b1 = b2.y * idv;
      acc00 += a2.x * b0; acc01 += a2.x * b1;
      acc10 += a2.y * b0; acc11 += a2.y * b1;
    }
  }
  int i0 = ib + ti * 2, j0 = tj * 2;
  float* Lk = Lmat + (size_t)k * 4096;
  Lk[i0 * 64 + j0]           = acc00 + (i0 == j0 ? 1.f : 0.f);
  Lk[i0 * 64 + j0 + 1]       = acc01;
  Lk[(i0 + 1) * 64 + j0]     = acc10;
  Lk[(i0 + 1) * 64 + j0 + 1] = acc11 + (i0 == j0 ? 1.f : 0.f);
}

// ---------------- S3: Cholesky + logdet + h ----------------
__global__ __launch_bounds__(256) void mfa_chol(const float* __restrict__ Lmat,
                                                const float* __restrict__ m2ws,
                                                const float* __restrict__ c0a,
                                                float* __restrict__ Cchol,
                                                float* __restrict__ invd,
                                                float* __restrict__ hws,
                                                float* __restrict__ c0) {
  int k = blockIdx.x, tid = threadIdx.x;
  __shared__ float Cm[64 * 65];
  __shared__ float red[64];
  for (int idx = tid; idx < 4096; idx += 256)
    Cm[(idx >> 6) * 65 + (idx & 63)] = Lmat[(size_t)k * 4096 + idx];
  __syncthreads();
  int tr = tid >> 4, tc = tid & 15;
  // Right-looking Cholesky. Diagonal kept RAW (= C[j][j]^2); columns scaled.
  for (int j = 0; j < 64; ++j) {
    float v = Cm[j * 65 + j];           // row j of col j: disjoint from writes below
    float inv = 1.0f / sqrtf(v);
    if (tid < 64 && tid > j) Cm[tid * 65 + j] *= inv;
    __syncthreads();
#pragma unroll
    for (int a = 0; a < 4; ++a)
#pragma unroll
      for (int b = 0; b < 4; ++b) {
        int r = j + 1 + tr + 16 * a;
        int c = j + 1 + tc + 16 * b;
        if (r < 64 && c < 64)
          Cm[r * 65 + c] -= Cm[r * 65 + j] * Cm[c * 65 + j];
      }
    __syncthreads();
  }
  // write C (strict lower = chol factor; diag raw; upper junk -- consumers only read i<j)
  for (int idx = tid; idx < 4096; idx += 256)
    Cchol[(size_t)k * 4096 + idx] = Cm[(idx >> 6) * 65 + (idx & 63)];
  if (tid < 64) red[tid] = logf(Cm[tid * 65 + tid]);   // log(diag raw) = log C_jj^2
  __syncthreads();
  if (tid == 0) {
    float s = 0.f;
    for (int q = 0; q < 64; ++q) s += red[q];          // = logdetL
    c0[k] = c0a[k] - 0.5f * s;
  }
  // h = C^{-1} m2 via wave-parallel forward substitution (wave 0)
  if (tid < 64) {
    int l = tid;
    float m2v = m2ws[k * 64 + l];
    float invdl = 1.0f / sqrtf(Cm[l * 65 + l]);
    float hl = 0.f;
    for (int r = 0; r < 64; ++r) {
      float contrib = (l < r) ? Cm[r * 65 + l] * hl : 0.f;
      contrib += __shfl_xor(contrib, 1, 64);
      contrib += __shfl_xor(contrib, 2, 64);
      contrib += __shfl_xor(contrib, 4, 64);
      contrib += __shfl_xor(contrib, 8, 64);
      contrib += __shfl_xor(contrib, 16, 64);
      contrib += __shfl_xor(contrib, 32, 64);
      if (l == r) hl = (m2v - contrib) * invdl;
    }
    hws[k * 64 + l] = hl;
    invd[k * 64 + l] = invdl;
  }
}

// helper: static component extract of float4 array (j compile-time after unroll)
#define A4C(arr, j) (((j) & 3) == 0 ? arr[(j) >> 2].x : ((j) & 3) == 1 ? arr[(j) >> 2].y \
                     : ((j) & 3) == 2 ? arr[(j) >> 2].z : arr[(j) >> 2].w)

// ---------------- S4: solve G C^T = AiD (per d-row), write Gt bf16 (8192 x 512) ----------------
__global__ __launch_bounds__(256) void mfa_solve(const float* __restrict__ A,
                                                 const float* __restrict__ iDf,
                                                 const float* __restrict__ Cchol,
                                                 const float* __restrict__ invd,
                                                 unsigned short* __restrict__ Gt) {
  int k = blockIdx.x, half = blockIdx.y, tid = threadIdx.x;
  __shared__ float Cl[64 * 64];
  __shared__ float invdl[64];
  __shared__ unsigned short Gls[256 * 67];
  for (int idx = tid; idx < 4096; idx += 256) Cl[idx] = Cchol[(size_t)k * 4096 + idx];
  if (tid < 64) invdl[tid] = invd[k * 64 + tid];
  __syncthreads();
  int d = half * 256 + tid;
  float idv = iDf[k * DF + d];
  float4 a4[16];
  const float4* Ar = reinterpret_cast<const float4*>(A + (size_t)(k * DF + d) * LF);
#pragma unroll
  for (int p = 0; p < 16; ++p) a4[p] = Ar[p];
  float g[64];
  const float4* C4 = reinterpret_cast<const float4*>(Cl);
#pragma unroll
  for (int j = 0; j < 64; ++j) {
    float s0 = A4C(a4, j) * idv, s1 = 0.f, s2 = 0.f, s3 = 0.f;
    int nf = j >> 2;
#pragma unroll
    for (int i4 = 0; i4 < nf; ++i4) {
      float4 c = C4[j * 16 + i4];
      s0 -= c.x * g[i4 * 4 + 0];
      s1 -= c.y * g[i4 * 4 + 1];
      s2 -= c.z * g[i4 * 4 + 2];
      s3 -= c.w * g[i4 * 4 + 3];
    }
#pragma unroll
    for (int i = nf * 4; i < j; ++i) s0 -= Cl[j * 64 + i] * g[i];
    g[j] = ((s0 + s1) + (s2 + s3)) * invdl[j];
  }
#pragma unroll
  for (int j = 0; j < 64; ++j) Gls[tid * 67 + j] = bfr(g[j]);
  __syncthreads();
  // transposed write-out: Gt[k*64+col][half*256 + 8m .. +8)
  int l = tid & 63, w = tid >> 6;
  for (int it = 0; it < 8; ++it) {
    int col = w * 16 + (l >> 2);
    int m = it * 4 + (l & 3);
    unsigned short tmp[8];
#pragma unroll
    for (int q = 0; q < 8; ++q) tmp[q] = Gls[(m * 8 + q) * 67 + col];
    uint4 val;
    val.x = (unsigned)tmp[0] | ((unsigned)tmp[1] << 16);
    val.y = (unsigned)tmp[2] | ((unsigned)tmp[3] << 16);
    val.z = (unsigned)tmp[4] | ((unsigned)tmp[5] << 16);
    val.w = (unsigned)tmp[6] | ((unsigned)tmp[7] << 16);
    *reinterpret_cast<uint4*>(&Gt[(size_t)(k * 64 + col) * DF + half * 256 + m * 8]) = val;
  }
}

// ---------------- Q: r1 = c0 + x.w ; r2 = -0.5 * x^2.iD  (bf16 MFMA, BN=128=all K) ----------------
__global__ __launch_bounds__(256) void mfa_q1(const unsigned short* __restrict__ xbf,
                                              const unsigned short* __restrict__ x2bf,
                                              const unsigned short* __restrict__ wbf,
                                              const unsigned short* __restrict__ iDbf,
                                              const float* __restrict__ c0,
                                              float* __restrict__ r1,
                                              float* __restrict__ r2) {
  int nb = blockIdx.x * 128;
  int z = blockIdx.y;
  const unsigned short* Ap = z ? x2bf : xbf;
  const unsigned short* Bp = z ? iDbf : wbf;
  float* outp = z ? r2 : r1;
  int tid = threadIdx.x, lane = tid & 63, w = tid >> 6, wx = w & 1, wy = w >> 1;
  __shared__ unsigned short As[128 * 64];
  __shared__ unsigned short Bs[128 * 64];
  f32x4 acc[4][4];
  f32x4 zero = {0.f, 0.f, 0.f, 0.f};
#pragma unroll
  for (int mi = 0; mi < 4; ++mi)
#pragma unroll
    for (int nj = 0; nj < 4; ++nj) acc[mi][nj] = zero;
  const unsigned short* xg = Ap + (size_t)nb * DF;
  int lr = lane >> 3, lc = lane & 7;
  for (int kt = 0; kt < 8; ++kt) {
#pragma unroll
    for (int it = 0; it < 4; ++it) {
      int row = w * 8 + it * 32 + lr;
      ldst16(&As[(w * 8 + it * 32) * 64], xg + (size_t)row * DF + kt * 64 + lc * 8);
      ldst16(&Bs[(w * 8 + it * 32) * 64], Bp + (size_t)row * DF + kt * 64 + lc * 8);
    }
    __syncthreads();
#pragma unroll
    for (int kk = 0; kk < 2; ++kk) {
      short8 av[4], bv[4];
#pragma unroll
      for (int mi = 0; mi < 4; ++mi)
        av[mi] = *reinterpret_cast<const short8*>(&As[(wy * 64 + mi * 16 + (lane & 15)) * 64 + kk * 32 + (lane >> 4) * 8]);
#pragma unroll
      for (int nj = 0; nj < 4; ++nj)
        bv[nj] = *reinterpret_cast<const short8*>(&Bs[(wx * 64 + nj * 16 + (lane & 15)) * 64 + kk * 32 + (lane >> 4) * 8]);
#pragma unroll
      for (int mi = 0; mi < 4; ++mi)
#pragma unroll
        for (int nj = 0; nj < 4; ++nj)
          acc[mi][nj] = __builtin_amdgcn_mfma_f32_16x16x32_bf16(av[mi], bv[nj], acc[mi][nj], 0, 0, 0);
    }
    __syncthreads();
  }
  // epilogue: D[row=n][col=k-comp]; C layout col=lane&15, row=quad*4+reg
#pragma unroll
  for (int mi = 0; mi < 4; ++mi)
#pragma unroll
    for (int nj = 0; nj < 4; ++nj) {
      int ccol = wx * 64 + nj * 16 + (lane & 15);
      int nrow = nb + wy * 64 + mi * 16 + (lane >> 4) * 4;
      float4 o;
      if (z == 0) {
        float c = c0[ccol];
        o.x = acc[mi][nj][0] + c; o.y = acc[mi][nj][1] + c;
        o.z = acc[mi][nj][2] + c; o.w = acc[mi][nj][3] + c;
      } else {
        o.x = -0.5f * acc[mi][nj][0]; o.y = -0.5f * acc[mi][nj][1];
        o.z = -0.5f * acc[mi][nj][2]; o.w = -0.5f * acc[mi][nj][3];
      }
      *reinterpret_cast<float4*>(&outp[(size_t)ccol * NN + nrow]) = o;
    }
}

// ---------------- M: main GEMM x @ Gbig + fused 0.5*||u-h||^2 epilogue ----------------
__global__ __launch_bounds__(256) void mfa_main(const unsigned short* __restrict__ xbf,
                                                const unsigned short* __restrict__ Gt,
                                                const float* __restrict__ hws,
                                                float* __restrict__ s2b) {
  int bx = blockIdx.x, by = blockIdx.y;
  int tid = threadIdx.x, lane = tid & 63, w = tid >> 6, wx = w & 1, wy = w >> 1;
  __shared__ unsigned short As[128 * 64];
  __shared__ unsigned short Bs[128 * 64];
  f32x4 acc[4][4];
  f32x4 zero = {0.f, 0.f, 0.f, 0.f};
#pragma unroll
  for (int mi = 0; mi < 4; ++mi)
#pragma unroll
    for (int nj = 0; nj < 4; ++nj) acc[mi][nj] = zero;
  int nbase = by * 128, cbase = bx * 128;
  const unsigned short* xg = xbf + (size_t)nbase * DF;
  const unsigned short* gg = Gt + (size_t)cbase * DF;
  int lr = lane >> 3, lc = lane & 7;
  for (int kt = 0; kt < 8; ++kt) {
#pragma unroll
    for (int it = 0; it < 4; ++it) {
      int row = w * 8 + it * 32 + lr;
      ldst16(&As[(w * 8 + it * 32) * 64], xg + (size_t)row * DF + kt * 64 + lc * 8);
      ldst16(&Bs[(w * 8 + it * 32) * 64], gg + (size_t)row * DF + kt * 64 + lc * 8);
    }
    __syncthreads();
#pragma unroll
    for (int kk = 0; kk < 2; ++kk) {
      short8 av[4], bv[4];
#pragma unroll
      for (int mi = 0; mi < 4; ++mi)
        av[mi] = *reinterpret_cast<const short8*>(&As[(wy * 64 + mi * 16 + (lane & 15)) * 64 + kk * 32 + (lane >> 4) * 8]);
#pragma unroll
      for (int nj = 0; nj < 4; ++nj)
        bv[nj] = *reinterpret_cast<const short8*>(&Bs[(wx * 64 + nj * 16 + (lane & 15)) * 64 + kk * 32 + (lane >> 4) * 8]);
#pragma unroll
      for (int mi = 0; mi < 4; ++mi)
#pragma unroll
        for (int nj = 0; nj < 4; ++nj)
          acc[mi][nj] = __builtin_amdgcn_mfma_f32_16x16x32_bf16(av[mi], bv[nj], acc[mi][nj], 0, 0, 0);
    }
    __syncthreads();
  }
  // epilogue: wave owns one component's 64 cols; sum (u-h)^2 over cols per row
  int comp = bx * 2 + wx;
  float hv[4];
#pragma unroll
  for (int nj = 0; nj < 4; ++nj) hv[nj] = hws[comp * 64 + nj * 16 + (lane & 15)];
  int rbase = nbase + wy * 64;
#pragma unroll
  for (int mi = 0; mi < 4; ++mi) {
#pragma unroll
    for (int reg = 0; reg < 4; ++reg) {
      float s = 0.f;
#pragma unroll
      for (int nj = 0; nj < 4; ++nj) {
        float dlt = acc[mi][nj][reg] - hv[nj];
        s += dlt * dlt;
      }
      s += __shfl_xor(s, 1, 64);
      s += __shfl_xor(s, 2, 64);
      s += __shfl_xor(s, 4, 64);
      s += __shfl_xor(s, 8, 64);
      if ((lane & 15) == 0)
        s2b[(size_t)comp * NN + rbase + mi * 16 + (lane >> 4) * 4 + reg] = 0.5f * s;
    }
  }
}

// ---------------- R: online logsumexp over K ----------------
__global__ __launch_bounds__(256) void mfa_lse(const float* __restrict__ r1,
                                               const float* __restrict__ r2,
                                               const float* __restrict__ s2b,
                                               float* __restrict__ out) {
  int n = blockIdx.x * 256 + threadIdx.x;
  float m = -3.0e38f, s = 0.f;
#pragma unroll 8
  for (int k = 0; k < KC; ++k) {
    float t = r1[(size_t)k * NN + n] + r2[(size_t)k * NN + n] + s2b[(size_t)k * NN + n];
    float nm = fmaxf(m, t);
    s = s * expf(m - nm) + expf(t - nm);
    m = nm;
  }
  out[n] = m + logf(s);
}

extern "C" void kernel_launch(void* const* d_in, const int* in_sizes, int n_in,
                              void* d_out, int out_size, void* d_ws, size_t ws_size,
                              hipStream_t stream) {
  const float* x  = (const float*)d_in[0];
  const float* MU = (const float*)d_in[1];
  const float* A  = (const float*)d_in[2];
  const float* Dp = (const float*)d_in[3];
  const float* PI = (const float*)d_in[4];
  float* out = (float*)d_out;

  char* base = (char*)d_ws;
  size_t off = 0;
  auto alloc = [&](size_t bytes) -> void* {
    void* p = base + off;
    off += (bytes + 255) & ~(size_t)255;
    return p;
  };
  unsigned short* xbf  = (unsigned short*)alloc((size_t)NN * DF * 2);
  unsigned short* x2bf = (unsigned short*)alloc((size_t)NN * DF * 2);
  float* iDf           = (float*)alloc((size_t)KC * DF * 4);
  unsigned short* iDbf = (unsigned short*)alloc((size_t)KC * DF * 2);
  unsigned short* wbf  = (unsigned short*)alloc((size_t)KC * DF * 2);
  float* m2ws          = (float*)alloc((size_t)KC * 64 * 4);
  float* c0a           = (float*)alloc((size_t)KC * 4);
  float* c0            = (float*)alloc((size_t)KC * 4);
  float* Lmat          = (float*)alloc((size_t)KC * 4096 * 4);
  float* Cchol         = (float*)alloc((size_t)KC * 4096 * 4);
  float* invd          = (float*)alloc((size_t)KC * 64 * 4);
  float* hws           = (float*)alloc((size_t)KC * 64 * 4);
  unsigned short* Gt   = (unsigned short*)alloc((size_t)KC * 64 * DF * 2);
  float* r1            = (float*)alloc((size_t)KC * NN * 4);
  float* r2            = (float*)alloc((size_t)KC * NN * 4);
  float* s2b           = (float*)alloc((size_t)KC * NN * 4);

  mfa_convert<<<NN * DF / 1024, 256, 0, stream>>>(x, xbf, x2bf);
  mfa_stats<<<KC, 256, 0, stream>>>(MU, Dp, A, PI, iDf, iDbf, wbf, m2ws, c0a);
  mfa_lmat<<<dim3(KC, 4), 256, 0, stream>>>(A, iDf, Lmat);
  mfa_chol<<<KC, 256, 0, stream>>>(Lmat, m2ws, c0a, Cchol, invd, hws, c0);
  mfa_solve<<<dim3(KC, 2), 256, 0, stream>>>(A, iDf, Cchol, invd, Gt);
  mfa_q1<<<dim3(NN / 128, 2), 256, 0, stream>>>(xbf, x2bf, wbf, iDbf, c0, r1, r2);
  mfa_main<<<dim3(64, 32), 256, 0, stream>>>(xbf, Gt, hws, s2b);
  mfa_lse<<<NN / 256, 256, 0, stream>>>(r1, r2, s2b, out);
}